// Round 2
// baseline (102.873 us; speedup 1.0000x reference)
//
#include <hip/hip_runtime.h>

// Fourier head: B=512, P=1024, K=64.
// out[b,p] = a0/(2P) + sum_k pa[b,k]*cos(c*x[b,p]*k) + pb[b,k]*sin(c*x[b,p]*k)
// pa = x @ a, pb = x @ b, c = 2*pi/P.  Inputs f32, output f32.
//
// Journal:
//  - Harness fixed cost ~65.5us/call. Kernel floor ~4us.
//  - R4: monolithic 2-rows/block, dur 71.8, kernel ~6.5us. Stage B reads
//    full a+b (512KB) per block -> 128MB aggregate @ ~33TB/s = the measured
//    aggregate-L2 roofline (~3.8us of the 6.5). Stage C VALU-bound 1.65us.
//  - R5 2-kernel split: +12us/node. R6 cooperative: ~40us idle. R7 pk-asm: 2x.
//  - R8 producer/consumer with AGENT-scope relaxed-load polls: FAILED (99.7).
//    fourier_pc=47us, VALUBusy 6% => polls served from stale L1/L2 (poison
//    lines resident), never saw flags, burned SPIN_MAX=5000 (~22cyc/iter,
//    L1-hit signature), then serial fallback. Partials traffic (FETCH 4.4MB,
//    WRITE 10.2MB) confirmed the data flow itself was correct.
//  - R9 (this): same cohort structure, sync transport fixed:
//      * flags via atomicExch / atomicOr(fp,0) RMW -- RMWs execute at the
//        coherence point, measured cross-XCD coherent [guide m20]; cannot
//        be cache-served stale.
//      * partials via SYSTEM-scope atomic store/load (sc0+sc1: bypass L1
//        and XCD-L2 -> immune to resident poison lines).
//      * SPIN_MAX=24 sweeps -> worst-case timeout ~5-15us, not 40us.
//    Readiness = two DIFFERENT magic words/producer: uniform poison can
//    never match both -> self-initializing flags, zero init cost. Stale
//    flags across iterations harmless (inputs restored -> partials
//    bit-identical). Timeout -> fallback recompute: deadlock impossible.

constexpr int PN = 1024;
constexpr int KN = 64;
constexpr int NBLK = 256;            // = #CUs; 1 block/CU -> co-residency
constexpr int NSLICE = 16;           // blocks per cohort = p-slices
constexpr int PSL = PN / NSLICE;     // 64 p per slice
constexpr int RG = 32;               // rows per cohort (16 blocks x 2 rows)
constexpr int PART_WORDS = RG * 2 * KN;   // 4096 f32 (16KB) per block
constexpr unsigned MAGIC1 = 0x9E3779B9u;
constexpr unsigned MAGIC2 = 0x85EBCA6Bu;
constexpr int SPIN_MAX = 24;         // sweeps; ~0.25-1us each at MALL latency

__global__ __launch_bounds__(256) void fourier_pc(
    const float* __restrict__ x,
    const float* __restrict__ a,
    const float* __restrict__ bco,
    const float* __restrict__ a0,
    float* __restrict__ out,
    float* __restrict__ ws,
    int use_pc)
{
    __shared__ float xs[RG][PSL + 1];    // 32x65 f32, +1 pad: conflict-free
    __shared__ float spab[2][2 * KN];    // pa/pb interleaved, stride-2
    __shared__ int sstate;               // 0 = partials ok, 1 = fallback

    const int t   = threadIdx.x;
    const int blk = blockIdx.x;
    const int row0 = 2 * blk;

    float*    partials = ws;
    unsigned* flags    = (unsigned*)(ws + (size_t)NBLK * PART_WORDS);

    if (use_pc) {
        const int rg = blk >> 4, sl = blk & 15;

        // ---- Producer stage: x-tile [32 rows][64 p] -> LDS ----
        {
            const int q = t & 15, rr = t >> 4;
            #pragma unroll
            for (int h = 0; h < 2; ++h) {
                const int row = rr + 16 * h;
                const float4 v = *(const float4*)(
                    x + (size_t)(rg * RG + row) * PN + sl * PSL + 4 * q);
                xs[row][4*q+0] = v.x; xs[row][4*q+1] = v.y;
                xs[row][4*q+2] = v.z; xs[row][4*q+3] = v.w;
            }
        }
        __syncthreads();

        // ---- Producer compute: 2 rows x 4k x {a,b} over 64 p ----
        // a/b slice = 32KB total -> L1/L2-resident; VALU-bound.
        const int kg = t & 15, rg2 = t >> 4;
        const int r0 = 2 * rg2, r1 = r0 + 1;
        float sa0[4] = {}, sb0[4] = {}, sa1[4] = {}, sb1[4] = {};
        const float* ap = a   + (size_t)sl * PSL * KN + 4 * kg;
        const float* bp = bco + (size_t)sl * PSL * KN + 4 * kg;
        #pragma unroll 4
        for (int p = 0; p < PSL; ++p) {
            const float4 av = *(const float4*)(ap + (size_t)p * KN);
            const float4 bv = *(const float4*)(bp + (size_t)p * KN);
            const float x0 = xs[r0][p];
            const float x1 = xs[r1][p];
            sa0[0] = fmaf(x0, av.x, sa0[0]); sa0[1] = fmaf(x0, av.y, sa0[1]);
            sa0[2] = fmaf(x0, av.z, sa0[2]); sa0[3] = fmaf(x0, av.w, sa0[3]);
            sb0[0] = fmaf(x0, bv.x, sb0[0]); sb0[1] = fmaf(x0, bv.y, sb0[1]);
            sb0[2] = fmaf(x0, bv.z, sb0[2]); sb0[3] = fmaf(x0, bv.w, sb0[3]);
            sa1[0] = fmaf(x1, av.x, sa1[0]); sa1[1] = fmaf(x1, av.y, sa1[1]);
            sa1[2] = fmaf(x1, av.z, sa1[2]); sa1[3] = fmaf(x1, av.w, sa1[3]);
            sb1[0] = fmaf(x1, bv.x, sb1[0]); sb1[1] = fmaf(x1, bv.y, sb1[1]);
            sb1[2] = fmaf(x1, bv.z, sb1[2]); sb1[3] = fmaf(x1, bv.w, sb1[3]);
        }

        // ---- Publish partials: SYSTEM-scope (sc0+sc1 write-through) ----
        float* base = partials + (size_t)blk * PART_WORDS;
        auto st2 = [&](float lo, float hi, int w) {
            union { float f[2]; unsigned long long u; } c;
            c.f[0] = lo; c.f[1] = hi;
            __hip_atomic_store((unsigned long long*)(base + w), c.u,
                               __ATOMIC_RELAXED, __HIP_MEMORY_SCOPE_SYSTEM);
        };
        st2(sa0[0], sa0[1], r0*128 +      4*kg    );
        st2(sa0[2], sa0[3], r0*128 +      4*kg + 2);
        st2(sb0[0], sb0[1], r0*128 + 64 + 4*kg    );
        st2(sb0[2], sb0[3], r0*128 + 64 + 4*kg + 2);
        st2(sa1[0], sa1[1], r1*128 +      4*kg    );
        st2(sa1[2], sa1[3], r1*128 +      4*kg + 2);
        st2(sb1[0], sb1[1], r1*128 + 64 + 4*kg    );
        st2(sb1[2], sb1[3], r1*128 + 64 + 4*kg + 2);

        __builtin_amdgcn_fence(__ATOMIC_RELEASE, "agent");
        __syncthreads();   // vmcnt(0) drain for ALL waves before flags
        if (t == 0) {
            atomicExch(&flags[2*blk+0], MAGIC1);   // RMW: coherence point
            atomicExch(&flags[2*blk+1], MAGIC2);
        }
    }

    // ---- Consumer pre-work (hides cohort skew): own rows + sincos ----
    const float c0 = a0[0] * (1.0f / (2.0f * (float)PN));
    const float tp = (float)(6.283185307179586 / (double)PN);  // 2*pi/P
    float c1v[2][4], s1v[2][4], t2v[2][4];
    #pragma unroll
    for (int r = 0; r < 2; ++r) {
        const float4 xv = *(const float4*)(x + (size_t)(row0 + r) * PN + 4 * t);
        const float th[4] = {tp*xv.x, tp*xv.y, tp*xv.z, tp*xv.w};
        #pragma unroll
        for (int j = 0; j < 4; ++j) {
            float s1, c1;
            __sincosf(th[j], &s1, &c1);
            c1v[r][j] = c1; s1v[r][j] = s1; t2v[r][j] = c1 + c1;
        }
    }

    // ---- Spin on cohort flags: RMW polls (cannot be cache-stale) ----
    if (t == 0) sstate = 1;             // default: fallback
    if (use_pc && t < 64) {
        const int cb = blk & ~15;
        bool done = (t >= 32);          // lanes 0..31 poll 16 blocks x 2 words
        const unsigned expect = (t & 1) ? MAGIC2 : MAGIC1;
        unsigned* fp = &flags[2*(cb + (t >> 1)) + (t & 1)];
        int it = 0; bool timeout = false;
        for (;;) {
            if (!done)
                done = (atomicOr(fp, 0u) == expect);   // RMW read @ MALL
            if (__all(done)) break;
            if (++it > SPIN_MAX) { timeout = true; break; }
        }
        if (t == 0) sstate = timeout ? 1 : 0;
    }
    __syncthreads();
    __builtin_amdgcn_fence(__ATOMIC_ACQUIRE, "agent");

    // ---- Reduce 16 slice-partials (or fallback recompute) -> spab ----
    {
        const int which = t >> 7;        // 0: pa, 1: pb
        const int r     = (t >> 6) & 1;
        const int k     = t & 63;
        float s = 0.f;
        if (sstate == 0) {
            const int cb = blk & ~15;
            const size_t off = (size_t)(2 * (blk & 15) + r) * 128 + which * 64 + k;
            float v[NSLICE];
            #pragma unroll
            for (int s2 = 0; s2 < NSLICE; ++s2) {
                unsigned u = __hip_atomic_load(
                    (unsigned*)(partials + (size_t)(cb + s2) * PART_WORDS + off),
                    __ATOMIC_RELAXED, __HIP_MEMORY_SCOPE_SYSTEM);
                v[s2] = __uint_as_float(u);
            }
            #pragma unroll
            for (int s2 = 0; s2 < NSLICE; ++s2) s += v[s2];
        } else {
            // correct-regardless slow path (taken only on spin timeout)
            const float* m  = which ? bco : a;
            const float* xr = x + (size_t)(row0 + r) * PN;
            #pragma unroll 8
            for (int p = 0; p < PN; ++p)
                s = fmaf(xr[p], m[(size_t)p * KN + k], s);
        }
        spab[r][2*k + which] = s;        // stride-2: 2-way bank alias, free
    }
    __syncthreads();

    // ---- Stage C: Chebyshev recurrence, 4 points/thread/row (as R4) ----
    #pragma unroll
    for (int r = 0; r < 2; ++r) {
        float cm1[4], sm1[4], cm2[4], sm2[4], acc[4];
        const float pa0 = spab[r][0];
        const float pa1 = spab[r][2];
        const float pb1 = spab[r][3];
        #pragma unroll
        for (int j = 0; j < 4; ++j) {
            cm2[j] = 1.f;        sm2[j] = 0.f;
            cm1[j] = c1v[r][j];  sm1[j] = s1v[r][j];
            acc[j] = fmaf(pa1, cm1[j], fmaf(pb1, sm1[j], c0 + pa0));
        }
        #pragma unroll 8
        for (int k = 2; k < KN; ++k) {
            const float2 pk = *(const float2*)&spab[r][2 * k];  // broadcast
            #pragma unroll
            for (int j = 0; j < 4; ++j) {
                const float ck = fmaf(t2v[r][j], cm1[j], -cm2[j]);
                const float sk = fmaf(t2v[r][j], sm1[j], -sm2[j]);
                acc[j] = fmaf(pk.x, ck, acc[j]);
                acc[j] = fmaf(pk.y, sk, acc[j]);
                cm2[j] = cm1[j]; cm1[j] = ck;
                sm2[j] = sm1[j]; sm1[j] = sk;
            }
        }
        float4 o; o.x = acc[0]; o.y = acc[1]; o.z = acc[2]; o.w = acc[3];
        ((float4*)(out + (size_t)(row0 + r) * PN))[t] = o;
    }
}

extern "C" void kernel_launch(void* const* d_in, const int* in_sizes, int n_in,
                              void* d_out, int out_size, void* d_ws, size_t ws_size,
                              hipStream_t stream) {
    const float* x  = (const float*)d_in[0];
    const float* a  = (const float*)d_in[1];
    const float* b  = (const float*)d_in[2];
    const float* a0 = (const float*)d_in[3];
    float* out = (float*)d_out;

    const int nblocks = (out_size / PN) / 2;  // = 256 (as R4)
    const size_t need = (size_t)NBLK * PART_WORDS * 4 + (size_t)NBLK * 2 * 4;
    const int use_pc = (d_ws != nullptr && ws_size >= need && nblocks == NBLK) ? 1 : 0;

    fourier_pc<<<dim3(nblocks), dim3(256), 0, stream>>>(
        x, a, b, a0, out, (float*)d_ws, use_pc);
}

// Round 3
// 86.432 us; speedup vs baseline: 1.1902x; 1.1902x over previous
//
#include <hip/hip_runtime.h>

// Fourier head: B=512, P=1024, K=64.
// out[b,p] = a0/(2P) + sum_k pa[b,k]*cos(c*x[b,p]*k) + pb[b,k]*sin(c*x[b,p]*k)
// pa = x @ a, pb = x @ b, c = 2*pi/P.  Inputs f32, output f32.
//
// Journal:
//  - Harness fixed cost ~65.5us/call. Practical dur floor ~69.5-70us.
//  - R4: monolithic 2-rows/block, dur 71.8, kernel ~6.5us. BEST.
//  - R5 2-kernel split: +12us/node. R6 cooperative grid.sync: ~40us idle.
//  - R7 pk-asm: defeats compiler regalloc, 2x. PLAIN fmaf ONLY.
//  - R8/R9 producer-consumer (cohorts share a+b via d_ws partials): FAILED
//    99.7/102.9. Agent-scope relaxed polls never observe flags (stale L1/L2
//    poison lines, 22cyc L1-hit spin signature); RMW polls are coherent but
//    cost us-scale per sweep under 8192-lane contention -> timeout -> serial
//    fallback. CONCLUSION: single-dispatch cross-block sync costs 10-60us on
//    this chip; the stage-B redundancy it would remove is worth ~2us. DEAD.
//  - Composed roofline of monolithic kernel: stageB >= 128MB/34.5TB/s =
//    3.7us (L2 port, ROWS-invariant: 7.4/R + 0.85R flat for R=2..4);
//    stageC >= 134G FMA/157TF = 1.7us (Chebyshev already 1 FMA/term;
//    Goertzel same op count; no f32 MFMA); overheads ~0.7us -> ~6.1us.
//  - R10 (this): R4 byte-identical EXCEPT sincos hoisted into stage A's
//    load shadow (inputs are the thread's own float4; no barrier needed).
//    Removes ~0.4us of serial post-reduce VALU. Expect kernel ~6.0us.

constexpr int PN = 1024;
constexpr int KN = 64;
constexpr int ROWS = 2;   // rows/block; grid = 256 = #CUs -> stage B reads
                          // a+b (512KB) once per block: 128MB L2 aggregate.

__global__ __launch_bounds__(256) void fourier_fused(
    const float* __restrict__ x,
    const float* __restrict__ a,
    const float* __restrict__ bco,
    const float* __restrict__ a0,
    float* __restrict__ out)
{
    __shared__ float xs[ROWS][PN];           // 8 KB
    __shared__ float red[2][ROWS][16][KN];   // 16 KB
    __shared__ float spab[ROWS][2 * KN];     // 1 KB, pa/pb interleaved

    const int t = threadIdx.x;
    const int b0 = blockIdx.x * ROWS;

    const float tp = (float)(6.283185307179586 / (double)PN);  // 2*pi/P

    // ---- Stage A: ROWS x-rows -> LDS (float4, 16B/lane coalesced) ----
    // + sincos pre-work hoisted into the load shadow: the 4 points this
    //   thread owns in stage C are exactly its own stage-A float4, so the
    //   8 __sincosf calls need no barrier and overlap stage B's first
    //   a/b load latency instead of sitting serially after the reduce.
    float c1v[ROWS][4], s1v[ROWS][4], t2v[ROWS][4];
    #pragma unroll
    for (int r = 0; r < ROWS; ++r) {
        float4 v = ((const float4*)(x + (size_t)(b0 + r) * PN))[t];
        xs[r][4 * t + 0] = v.x;
        xs[r][4 * t + 1] = v.y;
        xs[r][4 * t + 2] = v.z;
        xs[r][4 * t + 3] = v.w;
        const float th[4] = {tp * v.x, tp * v.y, tp * v.z, tp * v.w};
        #pragma unroll
        for (int j = 0; j < 4; ++j) {
            float s1, c1;
            __sincosf(th[j], &s1, &c1);
            c1v[r][j] = c1; s1v[r][j] = s1; t2v[r][j] = c1 + c1;
        }
    }
    __syncthreads();

    // ---- Stage B: pa[r][k] = sum_p xs[r][p]*a[p,k]; pb likewise ----
    // 256 threads = 16 k-groups (float4 along K) x 16 p-groups.
    // One wave's loads cover 1KB contiguous (4 full K-rows), coalesced.
    {
        const int kg = t & 15;               // k = 4*kg + j
        const int pg = t >> 4;               // p = pg + 16*i
        float sa[ROWS][4] = {};
        float sb[ROWS][4] = {};
        #pragma unroll 4
        for (int i = 0; i < 64; ++i) {
            const int p = pg + 16 * i;
            const float4 av = *(const float4*)(a   + p * KN + 4 * kg);
            const float4 bv = *(const float4*)(bco + p * KN + 4 * kg);
            #pragma unroll
            for (int r = 0; r < ROWS; ++r) {
                const float xv = xs[r][p];
                sa[r][0] = fmaf(xv, av.x, sa[r][0]);
                sa[r][1] = fmaf(xv, av.y, sa[r][1]);
                sa[r][2] = fmaf(xv, av.z, sa[r][2]);
                sa[r][3] = fmaf(xv, av.w, sa[r][3]);
                sb[r][0] = fmaf(xv, bv.x, sb[r][0]);
                sb[r][1] = fmaf(xv, bv.y, sb[r][1]);
                sb[r][2] = fmaf(xv, bv.z, sb[r][2]);
                sb[r][3] = fmaf(xv, bv.w, sb[r][3]);
            }
        }
        #pragma unroll
        for (int r = 0; r < ROWS; ++r) {
            #pragma unroll
            for (int j = 0; j < 4; ++j) {
                red[0][r][pg][4 * kg + j] = sa[r][j];
                red[1][r][pg][4 * kg + j] = sb[r][j];
            }
        }
    }
    __syncthreads();

    // ---- Reduce 16 p-groups: 2*ROWS*64 = 256 sums, one per thread ----
    {
        const int which = t >> 7;            // 0: pa, 1: pb
        const int r = (t >> 6) & (ROWS - 1);
        const int k = t & 63;
        float s = 0.f;
        #pragma unroll
        for (int pg = 0; pg < 16; ++pg) s += red[which][r][pg][k];
        spab[r][2 * k + which] = s;          // stride-2: 2-way bank alias, free
    }
    __syncthreads();

    // ---- Stage C: Chebyshev recurrence, 4 points/thread/row ----
    // c_k = 2c1*c_{k-1} - c_{k-2}; s_k likewise. 4 FMA per k per point.
    const float c0 = a0[0] * (1.0f / (2.0f * (float)PN));

    #pragma unroll
    for (int r = 0; r < ROWS; ++r) {
        float cm1[4], sm1[4], cm2[4], sm2[4], acc[4];
        const float pa0 = spab[r][0];
        const float pa1 = spab[r][2];
        const float pb1 = spab[r][3];
        #pragma unroll
        for (int j = 0; j < 4; ++j) {
            cm2[j] = 1.f;         sm2[j] = 0.f;       // k=0
            cm1[j] = c1v[r][j];   sm1[j] = s1v[r][j]; // k=1 (hoisted)
            acc[j] = fmaf(pa1, cm1[j], fmaf(pb1, sm1[j], c0 + pa0));
        }
        #pragma unroll 8
        for (int k = 2; k < KN; ++k) {
            const float2 pk = *(const float2*)&spab[r][2 * k];  // ds_read_b64
            #pragma unroll
            for (int j = 0; j < 4; ++j) {
                const float ck = fmaf(t2v[r][j], cm1[j], -cm2[j]);
                const float sk = fmaf(t2v[r][j], sm1[j], -sm2[j]);
                acc[j] = fmaf(pk.x, ck, acc[j]);
                acc[j] = fmaf(pk.y, sk, acc[j]);
                cm2[j] = cm1[j]; cm1[j] = ck;
                sm2[j] = sm1[j]; sm1[j] = sk;
            }
        }
        float4 o; o.x = acc[0]; o.y = acc[1]; o.z = acc[2]; o.w = acc[3];
        ((float4*)(out + (size_t)(b0 + r) * PN))[t] = o;
    }
}

extern "C" void kernel_launch(void* const* d_in, const int* in_sizes, int n_in,
                              void* d_out, int out_size, void* d_ws, size_t ws_size,
                              hipStream_t stream) {
    const float* x  = (const float*)d_in[0];
    const float* a  = (const float*)d_in[1];
    const float* b  = (const float*)d_in[2];
    const float* a0 = (const float*)d_in[3];
    float* out = (float*)d_out;

    const int nblocks = (out_size / PN) / ROWS;  // = 256
    fourier_fused<<<dim3(nblocks), dim3(256), 0, stream>>>(x, a, b, a0, out);
}

// Round 4
// 71.357 us; speedup vs baseline: 1.4417x; 1.2113x over previous
//
#include <hip/hip_runtime.h>

// Fourier head: B=512, P=1024, K=64.
// out[b,p] = a0/(2P) + sum_k pa[b,k]*cos(c*x[b,p]*k) + pb[b,k]*sin(c*x[b,p]*k)
// pa = x @ a, pb = x @ b, c = 2*pi/P.  Inputs f32, output f32 (R0-R2).
//
// Journal:
//  - Harness fixed cost ~65.5us/call (256MB d_ws poison fill @84% HBM +
//    input restores + inter-dispatch gaps). Kernel-side floor ~4us ->
//    practical dur floor ~69.5-70us.
//  - R4 (this code): dur 71.81, kernel ~6.5us. BEST. Composed roofline:
//    stageB >= 128MB a+b through L2 @34.5TB/s = 3.7us (ROWS-invariant:
//    7.4/R + 0.85R flat for R=2..4); stageC >= 134G FMA @157TF = 1.7us
//    (Chebyshev already 1 FMA/term; no f32 MFMA); overheads ~0.7us ->
//    floor ~6.1us. Measured 6.5 = within 6%.
//  - R5 2-kernel split: +12us per graph node. SINGLE DISPATCH ONLY.
//  - R6 cooperative grid.sync: 44us kernel, ~40us idle. NO GRID SYNC.
//  - R7 pk-asm ILP overlap: kernel ~12us. Inline asm defeats regalloc.
//  - R8/R9 producer-consumer cohorts via d_ws partials: FAILED 99.7/102.9.
//    Agent-scope relaxed polls read stale L1/L2 poison lines (22cyc L1-hit
//    spin signature); RMW polls are coherent but us-scale per sweep under
//    8192-lane contention -> timeout -> serial fallback. Single-dispatch
//    cross-block sync costs 10-60us on this chip; prize was ~2us. DEAD.
//  - R10 sincos hoist into stage A: FAILED 86.4 (kernel ~21us, VGPR 32->40,
//    SGPR 48->112). Pinning 24 sincos-result VGPRs across stage B's loop
//    destroyed its load pipelining (8 in-flight float4 -> ~2) -> stage B
//    went L2-latency-bound. STAGE B'S SCHEDULE IS FRAGILE: do not change
//    register liveness across it. Same lesson as R7.
//  - R11: exact R4 revert. This kernel is at its composed roofline.

constexpr int PN = 1024;
constexpr int KN = 64;
constexpr int ROWS = 2;   // rows/block; grid = 256 = #CUs -> stage B reads
                          // a+b (512KB) once per block: 128MB L2 aggregate.

__global__ __launch_bounds__(256) void fourier_fused(
    const float* __restrict__ x,
    const float* __restrict__ a,
    const float* __restrict__ bco,
    const float* __restrict__ a0,
    float* __restrict__ out)
{
    __shared__ float xs[ROWS][PN];           // 8 KB
    __shared__ float red[2][ROWS][16][KN];   // 16 KB
    __shared__ float spab[ROWS][2 * KN];     // 1 KB, pa/pb interleaved

    const int t = threadIdx.x;
    const int b0 = blockIdx.x * ROWS;

    // ---- Stage A: ROWS x-rows -> LDS (float4, 16B/lane coalesced) ----
    #pragma unroll
    for (int r = 0; r < ROWS; ++r) {
        float4 v = ((const float4*)(x + (size_t)(b0 + r) * PN))[t];
        xs[r][4 * t + 0] = v.x;
        xs[r][4 * t + 1] = v.y;
        xs[r][4 * t + 2] = v.z;
        xs[r][4 * t + 3] = v.w;
    }
    __syncthreads();

    // ---- Stage B: pa[r][k] = sum_p xs[r][p]*a[p,k]; pb likewise ----
    // 256 threads = 16 k-groups (float4 along K) x 16 p-groups.
    // One wave's loads cover 1KB contiguous (4 full K-rows), coalesced.
    {
        const int kg = t & 15;               // k = 4*kg + j
        const int pg = t >> 4;               // p = pg + 16*i
        float sa[ROWS][4] = {};
        float sb[ROWS][4] = {};
        #pragma unroll 4
        for (int i = 0; i < 64; ++i) {
            const int p = pg + 16 * i;
            const float4 av = *(const float4*)(a   + p * KN + 4 * kg);
            const float4 bv = *(const float4*)(bco + p * KN + 4 * kg);
            #pragma unroll
            for (int r = 0; r < ROWS; ++r) {
                const float xv = xs[r][p];
                sa[r][0] = fmaf(xv, av.x, sa[r][0]);
                sa[r][1] = fmaf(xv, av.y, sa[r][1]);
                sa[r][2] = fmaf(xv, av.z, sa[r][2]);
                sa[r][3] = fmaf(xv, av.w, sa[r][3]);
                sb[r][0] = fmaf(xv, bv.x, sb[r][0]);
                sb[r][1] = fmaf(xv, bv.y, sb[r][1]);
                sb[r][2] = fmaf(xv, bv.z, sb[r][2]);
                sb[r][3] = fmaf(xv, bv.w, sb[r][3]);
            }
        }
        #pragma unroll
        for (int r = 0; r < ROWS; ++r) {
            #pragma unroll
            for (int j = 0; j < 4; ++j) {
                red[0][r][pg][4 * kg + j] = sa[r][j];
                red[1][r][pg][4 * kg + j] = sb[r][j];
            }
        }
    }
    __syncthreads();

    // ---- Reduce 16 p-groups: 2*ROWS*64 = 256 sums, one per thread ----
    {
        const int which = t >> 7;            // 0: pa, 1: pb
        const int r = (t >> 6) & (ROWS - 1);
        const int k = t & 63;
        float s = 0.f;
        #pragma unroll
        for (int pg = 0; pg < 16; ++pg) s += red[which][r][pg][k];
        spab[r][2 * k + which] = s;          // stride-2: 2-way bank alias, free
    }
    __syncthreads();

    // ---- Stage C: Chebyshev recurrence, 4 points/thread/row ----
    // c_k = 2c1*c_{k-1} - c_{k-2}; s_k likewise. 4 FMA per k per point.
    const float c0 = a0[0] * (1.0f / (2.0f * (float)PN));
    const float tp = (float)(6.283185307179586 / (double)PN);  // 2*pi/P

    #pragma unroll
    for (int r = 0; r < ROWS; ++r) {
        float cm1[4], sm1[4], cm2[4], sm2[4], t2[4], acc[4];
        const float pa0 = spab[r][0];
        const float pa1 = spab[r][2];
        const float pb1 = spab[r][3];
        #pragma unroll
        for (int j = 0; j < 4; ++j) {
            const float th = tp * xs[r][4 * t + j];
            float c1, s1;
            __sincosf(th, &s1, &c1);
            t2[j]  = c1 + c1;
            cm2[j] = 1.f; sm2[j] = 0.f;      // k=0
            cm1[j] = c1;  sm1[j] = s1;       // k=1
            acc[j] = fmaf(pa1, c1, fmaf(pb1, s1, c0 + pa0));
        }
        #pragma unroll 8
        for (int k = 2; k < KN; ++k) {
            const float2 pk = *(const float2*)&spab[r][2 * k];  // ds_read_b64
            #pragma unroll
            for (int j = 0; j < 4; ++j) {
                const float ck = fmaf(t2[j], cm1[j], -cm2[j]);
                const float sk = fmaf(t2[j], sm1[j], -sm2[j]);
                acc[j] = fmaf(pk.x, ck, acc[j]);
                acc[j] = fmaf(pk.y, sk, acc[j]);
                cm2[j] = cm1[j]; cm1[j] = ck;
                sm2[j] = sm1[j]; sm1[j] = sk;
            }
        }
        float4 o; o.x = acc[0]; o.y = acc[1]; o.z = acc[2]; o.w = acc[3];
        ((float4*)(out + (size_t)(b0 + r) * PN))[t] = o;
    }
}

extern "C" void kernel_launch(void* const* d_in, const int* in_sizes, int n_in,
                              void* d_out, int out_size, void* d_ws, size_t ws_size,
                              hipStream_t stream) {
    const float* x  = (const float*)d_in[0];
    const float* a  = (const float*)d_in[1];
    const float* b  = (const float*)d_in[2];
    const float* a0 = (const float*)d_in[3];
    float* out = (float*)d_out;

    const int nblocks = (out_size / PN) / ROWS;  // = 256
    fourier_fused<<<dim3(nblocks), dim3(256), 0, stream>>>(x, a, b, a0, out);
}